// Round 9
// baseline (3620.577 us; speedup 1.0000x reference)
//
#include <hip/hip_runtime.h>

// Problem constants (B=16, N=M=1024, D=32)
constexpr int   NN       = 1024;
constexpr float EPSf     = 1e-3f;
constexpr int   MAX_ITER = 100;

#define K2      1442.6950408889634f     // (1/eps) * log2(e)
#define LN2f    0.6931471805599453f
#define LOGK    (-6.9314616f)           // log(1/1024 + 1e-8)
#define LOGK2   (-9.9999852269f)        // LOGK * log2(e)

#define EXP2F(x) __builtin_amdgcn_exp2f(x)   // 2^x
#define LOG2F(x) __builtin_amdgcn_logf(x)    // log2(x)
#define RCPF(x)  __builtin_amdgcn_rcpf(x)    // 1/x (1 ulp)

typedef _Float16 half8 __attribute__((ext_vector_type(8)));

// ---------------------------------------------------------------------------
// dist[b][p][q] = sum_d (A[b][p][d] - Bm[b][q][d])^2, stored fp16 (validated)
// ---------------------------------------------------------------------------
__global__ __launch_bounds__(256) void build_dist(
    const float* __restrict__ A, const float* __restrict__ Bm,
    _Float16* __restrict__ out)
{
    __shared__ float aLds[16 * 32];
    __shared__ float bLds[256 * 33];
    const int b  = blockIdx.x >> 6;
    const int pt = blockIdx.x & 63;
    const int t  = threadIdx.x;

    const float* Ab = A  + ((size_t)b * NN + pt * 16) * 32;
    const float* Bb = Bm + (size_t)b * NN * 32;

    if (t < 128) ((float4*)aLds)[t] = ((const float4*)Ab)[t];

    for (int qt = 0; qt < 4; ++qt) {
        __syncthreads();
        const float4* src = (const float4*)(Bb + qt * 256 * 32);
#pragma unroll
        for (int i = 0; i < 8; ++i) {
            int j = t + (i << 8);
            float4 val = src[j];
            int q = j >> 3, dd = (j & 7) << 2;
            float* dst = &bLds[q * 33 + dd];
            dst[0] = val.x; dst[1] = val.y; dst[2] = val.z; dst[3] = val.w;
        }
        __syncthreads();

        float br[32];
#pragma unroll
        for (int d = 0; d < 32; ++d) br[d] = bLds[t * 33 + d];

#pragma unroll
        for (int p = 0; p < 16; ++p) {
            float acc = 0.f;
#pragma unroll
            for (int d4 = 0; d4 < 8; ++d4) {
                float4 a4 = ((const float4*)(aLds + p * 32))[d4];
                float dx = a4.x - br[d4 * 4 + 0];
                float dy = a4.y - br[d4 * 4 + 1];
                float dz = a4.z - br[d4 * 4 + 2];
                float dw = a4.w - br[d4 * 4 + 3];
                acc += dx * dx + dy * dy + dz * dz + dw * dw;
            }
            out[((size_t)b * NN + pt * 16 + p) * NN + qt * 256 + t] = (_Float16)acc;
        }
    }
}

// ---------------------------------------------------------------------------
// Fused sweep: ONE pass over C per iteration.
//   - row LSE -> u_new (prev-iterate shift, classic-max fallback on guard)
//   - col partials S_j += t_ij / s_i  (row-softmax identity; shift-free)
// Grid 1024 x 256: b = blk&15 (XCD-pins batch slice), l = blk>>4.
// Wave handles 4 rows (2 pairs). Col partials: regs -> padded LDS ds_add
// -> part[b][l][1024]. done chain: all blocks compute done(it) from
// dflag[it-1] | errsum(it-1); block 0 persists dflag[it].
// ---------------------------------------------------------------------------
__global__ __launch_bounds__(256) void sweep(
    const _Float16* __restrict__ Cmat,
    float* __restrict__ u, const float* __restrict__ v,
    float* __restrict__ part, float* __restrict__ errpart,
    const float* __restrict__ errsum, int* __restrict__ dflag, int it)
{
    __shared__ float vk[1024];
    __shared__ float colLds[1056];   // padded: index c + (c>>5)
    __shared__ float red[4];
    __shared__ int s_done;
    const int tid = threadIdx.x, wave = tid >> 6, lane = tid & 63;
    const int b = blockIdx.x & 15, l = blockIdx.x >> 4;

    if (tid < 16) {
        float e = (it > 0) ? errsum[(tid << 7) + (it - 1)] : 1e9f;
        e += __shfl_xor(e, 1); e += __shfl_xor(e, 2);
        e += __shfl_xor(e, 4); e += __shfl_xor(e, 8);
        if (tid == 0) {
            int d = ((it > 0) ? dflag[it - 1] : 0) | (e < 1.6f ? 1 : 0);
            s_done = d;
            if (blockIdx.x == 0) dflag[it] = d;
        }
    }
    {
        float4 t4 = ((const float4*)(v + (b << 10)))[tid];
        t4.x *= K2; t4.y *= K2; t4.z *= K2; t4.w *= K2;
        ((float4*)vk)[tid] = t4;
    }
    for (int c = tid; c < 1056; c += 256) colLds[c] = 0.f;
    __syncthreads();
    if (s_done) return;   // frozen

    const _Float16* Cb = Cmat + ((size_t)b << 20);
    float* ub = u + (b << 10);
    const int row0 = (l << 4) + (wave << 2);

    float colacc[16];
#pragma unroll
    for (int i = 0; i < 16; ++i) colacc[i] = 0.f;
    float werr = 0.f;

#pragma unroll
    for (int pr = 0; pr < 2; ++pr) {
        const int r = row0 + 2 * pr;
        const half8* r0 = (const half8*)(Cb + (size_t)r * NN);
        const half8* r1 = (const half8*)(Cb + (size_t)(r + 1) * NN);
        const float uo0 = ub[r], uo1 = ub[r + 1];
        const float M0 = LOGK2 - uo0 * K2;
        const float M1 = LOGK2 - uo1 * K2;

        float x0[16], x1[16];
#pragma unroll
        for (int k = 0; k < 2; ++k) {
            const int m_ = lane + (k << 6);
            half8 c0 = r0[m_], c1 = r1[m_];
            float4 va = ((const float4*)vk)[2 * m_];
            float4 vb4 = ((const float4*)vk)[2 * m_ + 1];
            float vv[8] = {va.x, va.y, va.z, va.w, vb4.x, vb4.y, vb4.z, vb4.w};
#pragma unroll
            for (int j = 0; j < 8; ++j) {
                x0[8 * k + j] = fmaf((float)c0[j], -K2, vv[j]);
                x1[8 * k + j] = fmaf((float)c1[j], -K2, vv[j]);
            }
        }
        float s0 = 0.f, s1 = 0.f;
#pragma unroll
        for (int i = 0; i < 16; ++i) {
            x0[i] = EXP2F(x0[i] - M0);   // t in place
            x1[i] = EXP2F(x1[i] - M1);
            s0 += x0[i]; s1 += x1[i];
        }
#pragma unroll
        for (int off = 32; off > 0; off >>= 1) {
            s0 += __shfl_xor(s0, off);
            s1 += __shfl_xor(s1, off);
        }
        float sh0 = M0, sh1 = M1;
        if (__builtin_expect(!(s0 >= 1e-27f && s0 <= 1e38f) ||
                             !(s1 >= 1e-27f && s1 <= 1e38f), 0)) {
            // classic max-shifted fallback (all rows at it=0)
#pragma unroll
            for (int k = 0; k < 2; ++k) {
                const int m_ = lane + (k << 6);
                half8 c0 = r0[m_], c1 = r1[m_];
                float4 va = ((const float4*)vk)[2 * m_];
                float4 vb4 = ((const float4*)vk)[2 * m_ + 1];
                float vv[8] = {va.x, va.y, va.z, va.w, vb4.x, vb4.y, vb4.z, vb4.w};
#pragma unroll
                for (int j = 0; j < 8; ++j) {
                    x0[8 * k + j] = fmaf((float)c0[j], -K2, vv[j]);
                    x1[8 * k + j] = fmaf((float)c1[j], -K2, vv[j]);
                }
            }
            float m0 = x0[0], m1 = x1[0];
#pragma unroll
            for (int i = 1; i < 16; ++i) { m0 = fmaxf(m0, x0[i]); m1 = fmaxf(m1, x1[i]); }
#pragma unroll
            for (int off = 32; off > 0; off >>= 1) {
                m0 = fmaxf(m0, __shfl_xor(m0, off));
                m1 = fmaxf(m1, __shfl_xor(m1, off));
            }
            s0 = 0.f; s1 = 0.f;
#pragma unroll
            for (int i = 0; i < 16; ++i) {
                x0[i] = EXP2F(x0[i] - m0);
                x1[i] = EXP2F(x1[i] - m1);
                s0 += x0[i]; s1 += x1[i];
            }
#pragma unroll
            for (int off = 32; off > 0; off >>= 1) {
                s0 += __shfl_xor(s0, off);
                s1 += __shfl_xor(s1, off);
            }
            sh0 = m0; sh1 = m1;
        }
        float n0 = EPSf * (LOGK - (sh0 + LOG2F(s0)) * LN2f);
        float n1 = EPSf * (LOGK - (sh1 + LOG2F(s1)) * LN2f);
        werr += fabsf(n0 - uo0) + fabsf(n1 - uo1);
        if (lane == 0) { ub[r] = n0; ub[r + 1] = n1; }
        float g0 = RCPF(s0), g1 = RCPF(s1);
#pragma unroll
        for (int i = 0; i < 16; ++i)
            colacc[i] = fmaf(x0[i], g0, fmaf(x1[i], g1, colacc[i]));
    }
#pragma unroll
    for (int k = 0; k < 2; ++k)
#pragma unroll
        for (int j = 0; j < 8; ++j) {
            int c = ((lane + (k << 6)) << 3) + j;
            atomicAdd(&colLds[c + (c >> 5)], colacc[8 * k + j]);
        }
    if (lane == 0) red[wave] = werr;
    __syncthreads();
    for (int c = tid; c < 1024; c += 256)
        part[(size_t)(((b << 6) + l) << 10) + c] = colLds[c + (c >> 5)];
    if (tid == 0) errpart[(b << 6) + l] = red[0] + red[1] + red[2] + red[3];
}

// ---------------------------------------------------------------------------
// Finalize: reduce part -> S_j, v_new = eps*(LOGK - ln2*(Mv_j + log2 S_j));
// Mv_j = LOGK2 - v_old_j*K2 is EXACT (identity), so the only failure mode is
// S underflow -> wave-cooperative classic LSE from the CT column. Also
// reduces errpart -> errsum[b][it]. Grid 64 x 256 (4 blocks/batch).
// ---------------------------------------------------------------------------
__global__ __launch_bounds__(256) void finalize(
    const _Float16* __restrict__ CTmat,
    const float* __restrict__ u, float* __restrict__ v,
    const float* __restrict__ part, const float* __restrict__ errpart,
    float* __restrict__ err, const int* __restrict__ dflag, int it)
{
    const int tid = threadIdx.x, lane = tid & 63;
    const int b = blockIdx.x >> 2, q = blockIdx.x & 3;
    if (dflag[it]) return;   // frozen

    if (q == 0 && tid < 64) {
        float e = errpart[(b << 6) + tid];
#pragma unroll
        for (int off = 32; off > 0; off >>= 1) e += __shfl_xor(e, off);
        if (tid == 0) err[(b << 7) + it] = e;
    }

    const float* pb = part + ((size_t)b << 16);
    const float* ub = u + (b << 10);
    float* vb = v + (b << 10);
    const int col = (q << 8) + tid;

    float S = 0.f;
#pragma unroll 8
    for (int l = 0; l < 64; ++l) S += pb[(l << 10) + col];
    float vold = vb[col];
    bool ok = (S >= 1e-27f && S <= 1e38f);
    float vnew = 0.f;
    if (ok) vnew = EPSf * (LOGK - ((LOGK2 - vold * K2) + LOG2F(S)) * LN2f);

    unsigned long long mask = __ballot(!ok);
    while (mask) {
        int src = __ffsll(mask) - 1;
        mask &= mask - 1;
        int fcol = __shfl(col, src);
        const half8* ct = (const half8*)(CTmat + ((size_t)b << 20) + (size_t)fcol * NN);
        float y[16];
#pragma unroll
        for (int k = 0; k < 2; ++k) {
            const int m_ = lane + (k << 6);
            half8 c8 = ct[m_];
            float4 ua = ((const float4*)ub)[2 * m_];
            float4 ub4 = ((const float4*)ub)[2 * m_ + 1];
            float uu[8] = {ua.x, ua.y, ua.z, ua.w, ub4.x, ub4.y, ub4.z, ub4.w};
#pragma unroll
            for (int j = 0; j < 8; ++j)
                y[8 * k + j] = fmaf((float)c8[j], -K2, uu[j] * K2);
        }
        float mm = y[0];
#pragma unroll
        for (int i = 1; i < 16; ++i) mm = fmaxf(mm, y[i]);
#pragma unroll
        for (int off = 32; off > 0; off >>= 1) mm = fmaxf(mm, __shfl_xor(mm, off));
        float ss = 0.f;
#pragma unroll
        for (int i = 0; i < 16; ++i) ss += EXP2F(y[i] - mm);
#pragma unroll
        for (int off = 32; off > 0; off >>= 1) ss += __shfl_xor(ss, off);
        float vf = EPSf * (LOGK - (mm + LOG2F(ss)) * LN2f);
        if (lane == src) vnew = vf;
    }
    vb[col] = vnew;
}

// ---------------------------------------------------------------------------
// cost = mean_b sum_ij exp((u_i + v_j - C_ij)/eps) * C_ij   (validated)
// ---------------------------------------------------------------------------
__global__ __launch_bounds__(256) void cost_kernel(
    const _Float16* __restrict__ C, const float* __restrict__ u,
    const float* __restrict__ v, float* __restrict__ out)
{
    __shared__ float ldsv[1024];
    __shared__ float red[4];
    const int tid = threadIdx.x, wave = tid >> 6, lane = tid & 63;
    const int b = blockIdx.x >> 5, l = blockIdx.x & 31;

    ((float4*)ldsv)[tid] = ((const float4*)(v + (b << 10)))[tid];
    __syncthreads();

    const _Float16* Cb = C + ((size_t)b << 20);
    const float* ub = u + (b << 10);
    const float4* V4 = (const float4*)ldsv;
    float csum = 0.f;
    for (int rr = 0; rr < 8; ++rr) {
        const int row = (l << 5) + (wave << 3) + rr;
        const float ui = ub[row];
        const half8* Crow = (const half8*)(Cb + (size_t)row * NN);
#pragma unroll
        for (int k = 0; k < 2; ++k) {
            const int m = lane + (k << 6);
            half8 c8 = Crow[m];
            float4 va = V4[2 * m];
            float4 vb4 = V4[2 * m + 1];
            float vv[8] = {va.x, va.y, va.z, va.w, vb4.x, vb4.y, vb4.z, vb4.w};
#pragma unroll
            for (int j = 0; j < 8; ++j) {
                float c = (float)c8[j];
                csum += EXP2F((ui + vv[j] - c) * K2) * c;
            }
        }
    }
#pragma unroll
    for (int off = 32; off > 0; off >>= 1) csum += __shfl_xor(csum, off);
    if (lane == 0) red[wave] = csum;
    __syncthreads();
    if (tid == 0)
        atomicAdd(out, (red[0] + red[1] + red[2] + red[3]) * (1.0f / 16.0f));
}

extern "C" void kernel_launch(void* const* d_in, const int* in_sizes, int n_in,
                              void* d_out, int out_size, void* d_ws, size_t ws_size,
                              hipStream_t stream) {
    const float* x = (const float*)d_in[0];  // output: [16,1024,32] fp32
    const float* y = (const float*)d_in[1];  // labels: [16,1024,32] fp32

    char* wsb = (char*)d_ws;
    _Float16* C  = (_Float16*)wsb;                   // 32 MB
    _Float16* CT = (_Float16*)(wsb + 33554432);      // 32 MB
    float* u       = (float*)(wsb + 67108864);       // 16384
    float* v       = u + 16384;                      // 16384
    float* err     = v + 16384;                      // 16 x 128
    int*   dflag   = (int*)(err + 2048);             // 128
    float* errpart = (float*)(dflag + 128);          // 1024
    float* part    = errpart + 1024;                 // 16*64*1024 (4 MB)
    float* out     = (float*)d_out;

    // zero u, v, err, dflag (contiguous); errpart/part are write-first
    (void)hipMemsetAsync(u, 0, (size_t)(2 * 16384 + 2048 + 128) * 4, stream);
    (void)hipMemsetAsync(out, 0, sizeof(float), stream);

    build_dist<<<dim3(16 * 64), dim3(256), 0, stream>>>(x, y, C);
    build_dist<<<dim3(16 * 64), dim3(256), 0, stream>>>(y, x, CT);

    for (int it = 0; it < MAX_ITER; ++it) {
        sweep<<<dim3(1024), dim3(256), 0, stream>>>(C, u, v, part, errpart,
                                                    err, dflag, it);
        finalize<<<dim3(64), dim3(256), 0, stream>>>(CT, u, v, part, errpart,
                                                     err, dflag, it);
    }

    cost_kernel<<<dim3(512), dim3(256), 0, stream>>>(C, u, v, out);
}

// Round 11
// 2344.223 us; speedup vs baseline: 1.5445x; 1.5445x over previous
//
#include <hip/hip_runtime.h>

// Problem constants (B=16, N=M=1024, D=32)
constexpr int   NN       = 1024;
constexpr float EPSf     = 1e-3f;
constexpr int   MAX_ITER = 100;

#define K2      1442.6950408889634f     // (1/eps) * log2(e)
#define LN2f    0.6931471805599453f
#define LOGK    (-6.9314616f)           // log(1/1024 + 1e-8)
#define LOGK2   (-9.9999852269f)        // LOGK * log2(e)

#define EXP2F(x) __builtin_amdgcn_exp2f(x)   // 2^x
#define LOG2F(x) __builtin_amdgcn_logf(x)    // log2(x)
#define RCPF(x)  __builtin_amdgcn_rcpf(x)    // 1/x (1 ulp)

typedef _Float16 half8 __attribute__((ext_vector_type(8)));

// ---------------------------------------------------------------------------
// dist[b][p][q] = sum_d (A[b][p][d] - Bm[b][q][d])^2, stored fp16 (validated)
// ---------------------------------------------------------------------------
__global__ __launch_bounds__(256) void build_dist(
    const float* __restrict__ A, const float* __restrict__ Bm,
    _Float16* __restrict__ out)
{
    __shared__ float aLds[16 * 32];
    __shared__ float bLds[256 * 33];
    const int b  = blockIdx.x >> 6;
    const int pt = blockIdx.x & 63;
    const int t  = threadIdx.x;

    const float* Ab = A  + ((size_t)b * NN + pt * 16) * 32;
    const float* Bb = Bm + (size_t)b * NN * 32;

    if (t < 128) ((float4*)aLds)[t] = ((const float4*)Ab)[t];

    for (int qt = 0; qt < 4; ++qt) {
        __syncthreads();
        const float4* src = (const float4*)(Bb + qt * 256 * 32);
#pragma unroll
        for (int i = 0; i < 8; ++i) {
            int j = t + (i << 8);
            float4 val = src[j];
            int q = j >> 3, dd = (j & 7) << 2;
            float* dst = &bLds[q * 33 + dd];
            dst[0] = val.x; dst[1] = val.y; dst[2] = val.z; dst[3] = val.w;
        }
        __syncthreads();

        float br[32];
#pragma unroll
        for (int d = 0; d < 32; ++d) br[d] = bLds[t * 33 + d];

#pragma unroll
        for (int p = 0; p < 16; ++p) {
            float acc = 0.f;
#pragma unroll
            for (int d4 = 0; d4 < 8; ++d4) {
                float4 a4 = ((const float4*)(aLds + p * 32))[d4];
                float dx = a4.x - br[d4 * 4 + 0];
                float dy = a4.y - br[d4 * 4 + 1];
                float dz = a4.z - br[d4 * 4 + 2];
                float dw = a4.w - br[d4 * 4 + 3];
                acc += dx * dx + dy * dy + dz * dz + dw * dw;
            }
            out[((size_t)b * NN + pt * 16 + p) * NN + qt * 256 + t] = (_Float16)acc;
        }
    }
}

// ---------------------------------------------------------------------------
// One fused Sinkhorn iteration, ONE launch. Grid 512 x 256:
// b = blk&15, l = blk>>4 (32 blocks/batch, 32 rows each).
// Phase A: freeze-flag chain from err table (r9-validated).
// Phase B: materialize v_{it-1} = f(S[it-1], v_{it-2}) — every block computes
//          all 1024 cols (redundant, deterministic); l==0 writes the parity
//          buffer; guard-fail -> wave-cooperative classic LSE from CT column.
// Phase C: row sweep of C: u_new (prev-iterate shift + classic fallback) and
//          column partials S_j += t/s, LDS-reduced then atomicAdd to S[it].
// All cross-block communication crosses kernel boundaries (S slabs per
// iteration, v parity-double-buffered) — no device sync anywhere.
// ---------------------------------------------------------------------------
__global__ __launch_bounds__(256) void step(
    const _Float16* __restrict__ Cmat, const _Float16* __restrict__ CTmat,
    float* __restrict__ u, float* __restrict__ v0, float* __restrict__ v1,
    float* __restrict__ S, float* __restrict__ err, int* __restrict__ dflag,
    int it, int last)
{
    __shared__ float vk[1024];
    __shared__ float colLds[1056];   // padded: index c + (c>>5)
    __shared__ float red[4];
    __shared__ int s_prev, s_cur;
    const int tid = threadIdx.x, wave = tid >> 6, lane = tid & 63;
    const int b = blockIdx.x & 15, l = blockIdx.x >> 4;

    // ---- phase A: freeze flags ----
    if (tid < 16) {
        float e = (it > 0) ? err[(tid << 7) + (it - 1)] : 1e9f;
        e += __shfl_xor(e, 1); e += __shfl_xor(e, 2);
        e += __shfl_xor(e, 4); e += __shfl_xor(e, 8);
        if (tid == 0) {
            int p = (it > 0) ? dflag[it - 1] : 0;
            int d = p | (e < 1.6f ? 1 : 0);
            s_prev = p; s_cur = d;
            if (blockIdx.x == 0 && !last) dflag[it] = d;
        }
    }
    __syncthreads();
    const int prevdone = s_prev, curdone = s_cur;
    const float* ub_c = u + (b << 10);

    // ---- phase B: materialize v_{it-1} ----
    if (it == 0) {
        for (int c = tid; c < 1024; c += 256) vk[c] = 0.f;
    } else if (!prevdone) {
        const float* vrd = (((it - 1) & 1) ? v1 : v0) + (b << 10);
        float*       vwr = (((it)     & 1) ? v1 : v0) + (b << 10);
        const float* Sp  = S + (size_t)(it - 1) * 16384 + (b << 10);
#pragma unroll
        for (int k = 0; k < 4; ++k) {
            const int c = (k << 8) + tid;
            float Sv = Sp[c];
            float vold = vrd[c];
            bool ok = (Sv >= 1e-27f && Sv <= 1e38f);
            float vnew = 0.f;
            if (ok) vnew = EPSf * (LOGK - ((LOGK2 - vold * K2) + LOG2F(Sv)) * LN2f);
            unsigned long long mask = __ballot(!ok);
            while (mask) {   // rare: classic column LSE from CT
                int src = __ffsll((unsigned long long)mask) - 1;
                mask &= mask - 1;
                int fcol = __shfl(c, src);
                const half8* ct = (const half8*)(CTmat + ((size_t)b << 20) +
                                                 (size_t)fcol * NN);
                float y[16];
#pragma unroll
                for (int kk = 0; kk < 2; ++kk) {
                    const int m_ = lane + (kk << 6);
                    half8 c8 = ct[m_];
                    float4 ua = ((const float4*)ub_c)[2 * m_];
                    float4 ub4 = ((const float4*)ub_c)[2 * m_ + 1];
                    float uu[8] = {ua.x, ua.y, ua.z, ua.w, ub4.x, ub4.y, ub4.z, ub4.w};
#pragma unroll
                    for (int j = 0; j < 8; ++j)
                        y[8 * kk + j] = fmaf((float)c8[j], -K2, uu[j] * K2);
                }
                float mm = y[0];
#pragma unroll
                for (int i = 1; i < 16; ++i) mm = fmaxf(mm, y[i]);
#pragma unroll
                for (int off = 32; off > 0; off >>= 1) mm = fmaxf(mm, __shfl_xor(mm, off));
                float ss = 0.f;
#pragma unroll
                for (int i = 0; i < 16; ++i) ss += EXP2F(y[i] - mm);
#pragma unroll
                for (int off = 32; off > 0; off >>= 1) ss += __shfl_xor(ss, off);
                float vf = EPSf * (LOGK - (mm + LOG2F(ss)) * LN2f);
                if (lane == src) vnew = vf;
            }
            if (l == 0) vwr[c] = vnew;
            vk[c] = vnew * K2;
        }
    }

    for (int c = tid; c < 1056; c += 256) colLds[c] = 0.f;
    __syncthreads();
    if (curdone || last) return;   // frozen (or materialize-only epilogue)

    // ---- phase C: row sweep ----
    const _Float16* Cb = Cmat + ((size_t)b << 20);
    float* ub = u + (b << 10);
    float colacc[16];
#pragma unroll
    for (int i = 0; i < 16; ++i) colacc[i] = 0.f;
    float werr = 0.f;

#pragma unroll
    for (int pr = 0; pr < 4; ++pr) {
        const int r = (l << 5) + (wave << 3) + (pr << 1);
        const half8* r0 = (const half8*)(Cb + (size_t)r * NN);
        const half8* r1 = (const half8*)(Cb + (size_t)(r + 1) * NN);
        const float uo0 = ub[r], uo1 = ub[r + 1];
        const float M0 = LOGK2 - uo0 * K2;
        const float M1 = LOGK2 - uo1 * K2;

        float x0[16], x1[16];
#pragma unroll
        for (int k = 0; k < 2; ++k) {
            const int m_ = lane + (k << 6);
            half8 c0 = r0[m_], c1 = r1[m_];
            float4 va = ((const float4*)vk)[2 * m_];
            float4 vb4 = ((const float4*)vk)[2 * m_ + 1];
            float vv[8] = {va.x, va.y, va.z, va.w, vb4.x, vb4.y, vb4.z, vb4.w};
#pragma unroll
            for (int j = 0; j < 8; ++j) {
                x0[8 * k + j] = fmaf((float)c0[j], -K2, vv[j]);
                x1[8 * k + j] = fmaf((float)c1[j], -K2, vv[j]);
            }
        }
        float s0 = 0.f, s1 = 0.f;
#pragma unroll
        for (int i = 0; i < 16; ++i) {
            x0[i] = EXP2F(x0[i] - M0);
            x1[i] = EXP2F(x1[i] - M1);
            s0 += x0[i]; s1 += x1[i];
        }
#pragma unroll
        for (int off = 32; off > 0; off >>= 1) {
            s0 += __shfl_xor(s0, off);
            s1 += __shfl_xor(s1, off);
        }
        float sh0 = M0, sh1 = M1;
        if (__builtin_expect(!(s0 >= 1e-27f && s0 <= 1e38f) ||
                             !(s1 >= 1e-27f && s1 <= 1e38f), 0)) {
            // classic max-shifted fallback (all rows at it=0)
#pragma unroll
            for (int k = 0; k < 2; ++k) {
                const int m_ = lane + (k << 6);
                half8 c0 = r0[m_], c1 = r1[m_];
                float4 va = ((const float4*)vk)[2 * m_];
                float4 vb4 = ((const float4*)vk)[2 * m_ + 1];
                float vv[8] = {va.x, va.y, va.z, va.w, vb4.x, vb4.y, vb4.z, vb4.w};
#pragma unroll
                for (int j = 0; j < 8; ++j) {
                    x0[8 * k + j] = fmaf((float)c0[j], -K2, vv[j]);
                    x1[8 * k + j] = fmaf((float)c1[j], -K2, vv[j]);
                }
            }
            float m0 = x0[0], m1 = x1[0];
#pragma unroll
            for (int i = 1; i < 16; ++i) { m0 = fmaxf(m0, x0[i]); m1 = fmaxf(m1, x1[i]); }
#pragma unroll
            for (int off = 32; off > 0; off >>= 1) {
                m0 = fmaxf(m0, __shfl_xor(m0, off));
                m1 = fmaxf(m1, __shfl_xor(m1, off));
            }
            s0 = 0.f; s1 = 0.f;
#pragma unroll
            for (int i = 0; i < 16; ++i) {
                x0[i] = EXP2F(x0[i] - m0);
                x1[i] = EXP2F(x1[i] - m1);
                s0 += x0[i]; s1 += x1[i];
            }
#pragma unroll
            for (int off = 32; off > 0; off >>= 1) {
                s0 += __shfl_xor(s0, off);
                s1 += __shfl_xor(s1, off);
            }
            sh0 = m0; sh1 = m1;
        }
        float n0 = EPSf * (LOGK - (sh0 + LOG2F(s0)) * LN2f);
        float n1 = EPSf * (LOGK - (sh1 + LOG2F(s1)) * LN2f);
        werr += fabsf(n0 - uo0) + fabsf(n1 - uo1);
        if (lane == 0) { ub[r] = n0; ub[r + 1] = n1; }
        float g0 = RCPF(s0), g1 = RCPF(s1);
#pragma unroll
        for (int i = 0; i < 16; ++i)
            colacc[i] = fmaf(x0[i], g0, fmaf(x1[i], g1, colacc[i]));
    }

#pragma unroll
    for (int k = 0; k < 2; ++k)
#pragma unroll
        for (int j = 0; j < 8; ++j) {
            int c = ((lane + (k << 6)) << 3) + j;
            atomicAdd(&colLds[c + (c >> 5)], colacc[8 * k + j]);
        }
    if (lane == 0) red[wave] = werr;
    __syncthreads();
    float* Sw = S + (size_t)it * 16384 + (b << 10);
    for (int c = tid; c < 1024; c += 256)
        atomicAdd(&Sw[c], colLds[c + (c >> 5)]);
    if (tid == 0)
        atomicAdd(&err[(b << 7) + it], red[0] + red[1] + red[2] + red[3]);
}

// ---------------------------------------------------------------------------
// T = first it with sum_b err[b][it] < 1.6 (else 99); pick v parity (T+1)&1;
// cost = mean_b sum_ij exp((u_i + v_j - C_ij)/eps) * C_ij
// ---------------------------------------------------------------------------
__global__ __launch_bounds__(256) void cost_kernel(
    const _Float16* __restrict__ C, const float* __restrict__ u,
    const float* __restrict__ v0, const float* __restrict__ v1,
    const float* __restrict__ err, float* __restrict__ out)
{
    __shared__ float ldsv[1024];
    __shared__ float red[4];
    __shared__ int sT;
    const int tid = threadIdx.x, wave = tid >> 6, lane = tid & 63;
    const int b = blockIdx.x >> 5, l = blockIdx.x & 31;

    if (tid == 0) sT = MAX_ITER - 1;
    __syncthreads();
    if (tid < MAX_ITER) {
        float s = 0.f;
#pragma unroll
        for (int bb = 0; bb < 16; ++bb) s += err[(bb << 7) + tid];
        if (s < 1.6f) atomicMin(&sT, tid);
    }
    __syncthreads();
    const int T = sT;

    const float* v = ((((T + 1) & 1) ? v1 : v0)) + (b << 10);
    ((float4*)ldsv)[tid] = ((const float4*)v)[tid];
    __syncthreads();

    const _Float16* Cb = C + ((size_t)b << 20);
    const float* ub = u + (b << 10);
    const float4* V4 = (const float4*)ldsv;
    float csum = 0.f;
    for (int rr = 0; rr < 8; ++rr) {
        const int row = (l << 5) + (wave << 3) + rr;
        const float ui = ub[row];
        const half8* Crow = (const half8*)(Cb + (size_t)row * NN);
#pragma unroll
        for (int k = 0; k < 2; ++k) {
            const int m = lane + (k << 6);
            half8 c8 = Crow[m];
            float4 va = V4[2 * m];
            float4 vb4 = V4[2 * m + 1];
            float vv[8] = {va.x, va.y, va.z, va.w, vb4.x, vb4.y, vb4.z, vb4.w};
#pragma unroll
            for (int j = 0; j < 8; ++j) {
                float c = (float)c8[j];
                csum += EXP2F((ui + vv[j] - c) * K2) * c;
            }
        }
    }
#pragma unroll
    for (int off = 32; off > 0; off >>= 1) csum += __shfl_xor(csum, off);
    if (lane == 0) red[wave] = csum;
    __syncthreads();
    if (tid == 0)
        atomicAdd(out, (red[0] + red[1] + red[2] + red[3]) * (1.0f / 16.0f));
}

extern "C" void kernel_launch(void* const* d_in, const int* in_sizes, int n_in,
                              void* d_out, int out_size, void* d_ws, size_t ws_size,
                              hipStream_t stream) {
    const float* x = (const float*)d_in[0];  // output: [16,1024,32] fp32
    const float* y = (const float*)d_in[1];  // labels: [16,1024,32] fp32

    char* wsb = (char*)d_ws;
    _Float16* C  = (_Float16*)wsb;                   // 32 MB
    _Float16* CT = (_Float16*)(wsb + (32u << 20));   // 32 MB
    float* u     = (float*)(wsb + (64u << 20));      // 16384
    float* v0    = u + 16384;                        // 16384
    float* v1    = v0 + 16384;                       // 16384
    float* err   = v1 + 16384;                       // 16 x 128
    int*   dflag = (int*)(err + 2048);               // 128
    float* S     = (float*)(dflag + 128);            // 100 x 16384 (6.55 MB)
    float* out   = (float*)d_out;

    // zero u, v0, v1, err, dflag, S (contiguous) + out
    (void)hipMemsetAsync(u, 0,
        (size_t)(3 * 16384 + 2048 + 128 + 100 * 16384) * 4, stream);
    (void)hipMemsetAsync(out, 0, sizeof(float), stream);

    build_dist<<<dim3(16 * 64), dim3(256), 0, stream>>>(x, y, C);
    build_dist<<<dim3(16 * 64), dim3(256), 0, stream>>>(y, x, CT);

    for (int it = 0; it <= MAX_ITER; ++it) {
        step<<<dim3(512), dim3(256), 0, stream>>>(
            C, CT, u, v0, v1, S, err, dflag, it, it == MAX_ITER ? 1 : 0);
    }

    cost_kernel<<<dim3(512), dim3(256), 0, stream>>>(C, u, v0, v1, err, out);
}